// Round 9
// baseline (342.797 us; speedup 1.0000x reference)
//
#include <hip/hip_runtime.h>
#include <hip/hip_cooperative_groups.h>
#include <cstddef>
#include <cstdint>

namespace cg = cooperative_groups;

typedef __attribute__((ext_vector_type(8))) short short8;
typedef __attribute__((ext_vector_type(4))) float f32x4;

namespace {
constexpr int B_   = 2;
constexpr int HW   = 16384;
constexpr int NTOT = 21504;
constexpr float SCALE = 0.088388347648318447f;  // 128^-0.5
}

__device__ __forceinline__ unsigned short f2bf(float f) {
    unsigned u = __builtin_bit_cast(unsigned, f);
    u += 0x7fffu + ((u >> 16) & 1u);
    return (unsigned short)(u >> 16);
}
__device__ __forceinline__ float bf2f(unsigned short h) {
    return __builtin_bit_cast(float, (unsigned)h << 16);
}
__device__ __forceinline__ float blo(unsigned u) {
    return __builtin_bit_cast(float, u << 16);
}
__device__ __forceinline__ float bhi(unsigned u) {
    return __builtin_bit_cast(float, u & 0xffff0000u);
}
__device__ __forceinline__ unsigned pk2(float a, float b) {
    return (unsigned)f2bf(a) | ((unsigned)f2bf(b) << 16);
}
__device__ __forceinline__ void gload_lds16(const void* g, void* l) {
    __builtin_amdgcn_global_load_lds(
        (const __attribute__((address_space(1))) void*)g,
        (__attribute__((address_space(3))) void*)l, 16, 0, 0);
}

// ===========================================================================
// Phase 1: vblock v in [0,1097):
//   0..519    transpose NCHW fp32 -> pixel-major bf16 (B,130,130,256), borders 0
//   520..1095 pack combined weights (key_w@conv_w | query_w@conv_w) -> B-frags
//   1096      combined bias
// fsm = 2KB float scratch (shared)
// ===========================================================================
__device__ __forceinline__ void phase_tp(
    int v, int tid,
    const float* __restrict__ feats, const float* __restrict__ cw,
    const float* __restrict__ kw, const float* __restrict__ qw,
    const float* __restrict__ cb, const float* __restrict__ kb,
    const float* __restrict__ qb, unsigned short* __restrict__ fpm,
    unsigned short* __restrict__ wp, float* __restrict__ bias,
    float* fsm)
{
    if (v < 520) {
        const int b = v >= 260;
        const int rem = v - b * 260;
        const int y = rem >> 1, xseg = rem & 1;
        const int lane = tid & 63, cg2 = tid >> 6;
        const int x = (xseg << 6) + lane;
        const bool inter = (y >= 1 && y <= 128);
        const float* src = feats + (((size_t)b * 256) << 14) + ((y - 1) << 7) + x;
        unsigned short* orow = fpm + ((size_t)(b * 130 + y) * 130 + 1 + x) * 256;

#pragma unroll
        for (int it = 0; it < 8; ++it) {
            const int c0 = (it << 5) + (cg2 << 3);
            uint4 w = {0u, 0u, 0u, 0u};
            if (inter) {
                float f0 = src[(size_t)(c0 + 0) << 14], f1 = src[(size_t)(c0 + 1) << 14];
                float f2 = src[(size_t)(c0 + 2) << 14], f3 = src[(size_t)(c0 + 3) << 14];
                float f4 = src[(size_t)(c0 + 4) << 14], f5 = src[(size_t)(c0 + 5) << 14];
                float f6 = src[(size_t)(c0 + 6) << 14], f7 = src[(size_t)(c0 + 7) << 14];
                w.x = pk2(f0, f1); w.y = pk2(f2, f3); w.z = pk2(f4, f5); w.w = pk2(f6, f7);
            }
            *(uint4*)(orow + c0) = w;
        }
        if (xseg == 0) {
            uint4 z = {0u, 0u, 0u, 0u};
            if (tid < 32)
                *(uint4*)(fpm + ((size_t)(b * 130 + y) * 130 + 0) * 256 + (tid << 3)) = z;
            else if (tid < 64)
                *(uint4*)(fpm + ((size_t)(b * 130 + y) * 130 + 129) * 256 + ((tid - 32) << 3)) = z;
        }
        return;
    }

    if (v == 1096) {
        float* cbv = fsm;   // 128 floats
        if (tid < 128) cbv[tid] = cb[tid];
        __syncthreads();
        const int oc = tid & 127, isQ = tid >> 7;
        const float* wrow = (isQ ? qw : kw) + oc * 128;
        float a = isQ ? qb[oc] : kb[oc];
        for (int j = 0; j < 128; ++j) a += wrow[j] * cbv[j];
        bias[tid] = a;
        __syncthreads();
        return;
    }

    // weight-pack: g in [0,576)
    float (*cvec)[4] = (float(*)[4])fsm;   // 128x4 floats
    const int g = v - 520;
    for (int idx = tid; idx < 512; idx += 256) {
        int j = idx >> 2, q = idx & 3;
        int pair = (g << 2) + q;
        int c = pair / 9, tap = pair - c * 9;
        cvec[j][q] = cw[j * 2304 + c * 9 + tap];
    }
    __syncthreads();
    const int oc = tid & 127, isQ = tid >> 7;
    const float* wrow = (isQ ? qw : kw) + oc * 128;
    float a0 = 0.f, a1 = 0.f, a2 = 0.f, a3 = 0.f;
    for (int j = 0; j < 128; ++j) {
        float wv = wrow[j];
        a0 += wv * cvec[j][0]; a1 += wv * cvec[j][1];
        a2 += wv * cvec[j][2]; a3 += wv * cvec[j][3];
    }
    float accs[4] = {a0, a1, a2, a3};
#pragma unroll
    for (int q = 0; q < 4; ++q) {
        int pair = (g << 2) + q;
        int c = pair / 9, tap = pair - c * 9;
        int chunk = c >> 5, kg = (c >> 3) & 3, i = c & 7;
        int nf = (isQ << 3) + (oc >> 4);
        int lane = (kg << 4) + (oc & 15);
        wp[((size_t)(((chunk * 9 + tap) << 4) + nf) << 9) + (lane << 3) + i] = f2bf(accs[q]);
    }
    __syncthreads();
}

// ===========================================================================
// Phase 2: conv3 body (R5/R7-proven). smem layout: abuf[2][7168] | obuf[64*264]
// ===========================================================================
__device__ __forceinline__ void phase_conv(
    int bid, int tid,
    const unsigned short* __restrict__ fpm, const unsigned short* __restrict__ wp,
    const float* __restrict__ kqbias, unsigned short* __restrict__ kT,
    unsigned short* __restrict__ qT, unsigned short* __restrict__ kT2,
    unsigned short* __restrict__ qT2, unsigned short* __restrict__ kT3,
    unsigned short* __restrict__ qT3, unsigned char* smem)
{
    unsigned short* obuf = (unsigned short*)(smem + 14336);

    const int w = tid >> 6, lane = tid & 63;
    const int b = bid >> 8, tile = bid & 255;
    const int ty0 = (tile >> 4) << 3, tx0 = (tile & 15) << 3;
    const int r = lane & 15, g = lane >> 4;

    const int sp_sub = lane >> 2, sp_o = (lane & 3) << 4;
    const int pbase = (((r >> 3) * 10) + (r & 7)) * 64 + (g << 4);
    const unsigned char* wpB = (const unsigned char*)wp + ((w << 2) << 10) + (lane << 4);

    f32x4 acc[4][4];
#pragma unroll
    for (int mi = 0; mi < 4; ++mi)
#pragma unroll
        for (int ni = 0; ni < 4; ++ni) acc[mi][ni] = (f32x4){0.f, 0.f, 0.f, 0.f};

    auto stage = [&](int chunk, int buf) {
#pragma unroll
        for (int k = 0; k < 2; ++k) {
            int i = w + (k << 2);
            if (i < 7) {
                int pl0 = (i << 4) + sp_sub;
                int y = (pl0 * 6554) >> 16;
                int x = pl0 - y * 10;
                const unsigned char* src = (const unsigned char*)fpm +
                    (((size_t)((b * 130 + ty0 + y) * 130 + tx0 + x)) << 9) +
                    (chunk << 6) + sp_o;
                gload_lds16(src, smem + buf * 7168 + (i << 10));
            }
        }
    };

    stage(0, 0);
    __syncthreads();

    for (int chunk = 0; chunk < 8; ++chunk) {
        const unsigned char* ab = smem + (chunk & 1) * 7168;
        if (chunk < 7) stage(chunk + 1, (chunk + 1) & 1);
        const unsigned char* wbase = wpB + (size_t)chunk * 147456;
#pragma unroll
        for (int tap = 0; tap < 9; ++tap) {
            const int dy = tap / 3, dx = tap % 3;
            short8 bf[4];
#pragma unroll
            for (int ni = 0; ni < 4; ++ni)
                bf[ni] = *(const short8*)(wbase + tap * 16384 + (ni << 10));
            short8 af[4];
#pragma unroll
            for (int mi = 0; mi < 4; ++mi)
                af[mi] = *(const short8*)(ab + pbase + (((2 * mi + dy) * 10 + dx) << 6));
#pragma unroll
            for (int mi = 0; mi < 4; ++mi)
#pragma unroll
                for (int ni = 0; ni < 4; ++ni)
                    acc[mi][ni] = __builtin_amdgcn_mfma_f32_16x16x32_bf16(
                        af[mi], bf[ni], acc[mi][ni], 0, 0, 0);
        }
        __syncthreads();
    }

    const int col = lane & 15;
    const int mrow0 = g << 2;
#pragma unroll
    for (int ni = 0; ni < 4; ++ni) {
        const int nf = (w << 2) + ni;
        const float bv = kqbias[(nf << 4) + col];
#pragma unroll
        for (int mi = 0; mi < 4; ++mi)
#pragma unroll
            for (int reg = 0; reg < 4; ++reg) {
                int m = mrow0 + reg;
                int pxl = ((2 * mi + (m >> 3)) << 3) + (m & 7);
                obuf[pxl * 264 + (nf << 4) + col] = f2bf(acc[mi][ni][reg] + bv);
            }
    }
    __syncthreads();

    {
        const int px = tid >> 2, q = tid & 3;
        const int gp = ((ty0 + (px >> 3)) << 7) + tx0 + (px & 7);
        const unsigned short* srow = obuf + px * 264 + (q << 6);
        unsigned short* dp = (q < 2)
            ? kT + ((((size_t)b << 14) + gp) << 7) + (q << 6)
            : qT + ((((size_t)b << 14) + gp) << 7) + ((q - 2) << 6);
#pragma unroll
        for (int j = 0; j < 8; ++j)
            *(uint4*)(dp + (j << 3)) = *(const uint4*)(srow + (j << 3));
    }

    {
        const int pp = tid >> 4, ocg = tid & 15, oc0 = ocg << 4;
        const int py2 = pp >> 2, px2 = pp & 3;
        const int gp2 = (((ty0 >> 1) + py2) << 6) + (tx0 >> 1) + px2;
        unsigned short* dp = (oc0 < 128)
            ? kT2 + (((size_t)b * 4096 + gp2) << 7) + oc0
            : qT2 + (((size_t)b * 4096 + gp2) << 7) + (oc0 - 128);
#pragma unroll
        for (int h = 0; h < 2; ++h) {
            float s0=0,s1=0,s2=0,s3=0,s4=0,s5=0,s6=0,s7=0;
#pragma unroll
            for (int dy = 0; dy < 2; ++dy)
#pragma unroll
                for (int dx = 0; dx < 2; ++dx) {
                    int pxl = (((py2 << 1) + dy) << 3) + (px2 << 1) + dx;
                    uint4 v = *(const uint4*)(obuf + pxl * 264 + oc0 + (h << 3));
                    s0 += blo(v.x); s1 += bhi(v.x); s2 += blo(v.y); s3 += bhi(v.y);
                    s4 += blo(v.z); s5 += bhi(v.z); s6 += blo(v.w); s7 += bhi(v.w);
                }
            uint4 o;
            o.x = pk2(s0 * 0.25f, s1 * 0.25f); o.y = pk2(s2 * 0.25f, s3 * 0.25f);
            o.z = pk2(s4 * 0.25f, s5 * 0.25f); o.w = pk2(s6 * 0.25f, s7 * 0.25f);
            *(uint4*)(dp + (h << 3)) = o;
        }
    }

    if (tid < 64) {
        const int pp = tid >> 4, ocg = tid & 15, oc0 = ocg << 4;
        const int py4 = pp >> 1, px4 = pp & 1;
        const int gp4 = (((ty0 >> 2) + py4) << 5) + (tx0 >> 2) + px4;
        unsigned short* dp = (oc0 < 128)
            ? kT3 + (((size_t)b * 1024 + gp4) << 7) + oc0
            : qT3 + (((size_t)b * 1024 + gp4) << 7) + (oc0 - 128);
#pragma unroll
        for (int h = 0; h < 2; ++h) {
            float s0=0,s1=0,s2=0,s3=0,s4=0,s5=0,s6=0,s7=0;
#pragma unroll
            for (int dy = 0; dy < 4; ++dy)
#pragma unroll
                for (int dx = 0; dx < 4; ++dx) {
                    int pxl = (((py4 << 2) + dy) << 3) + (px4 << 2) + dx;
                    uint4 v = *(const uint4*)(obuf + pxl * 264 + oc0 + (h << 3));
                    s0 += blo(v.x); s1 += bhi(v.x); s2 += blo(v.y); s3 += bhi(v.y);
                    s4 += blo(v.z); s5 += bhi(v.z); s6 += blo(v.w); s7 += bhi(v.w);
                }
            const float f = 0.0625f;
            uint4 o;
            o.x = pk2(s0 * f, s1 * f); o.y = pk2(s2 * f, s3 * f);
            o.z = pk2(s4 * f, s5 * f); o.w = pk2(s6 * f, s7 * f);
            *(uint4*)(dp + (h << 3)) = o;
        }
    }
}

// ===========================================================================
// Phase 3: gdot tile (256 thr: 64 pixels x 4 slices of 32 ch).
// v in [0,672). kwin = 36,864 B LDS.
// ===========================================================================
__device__ __forceinline__ void phase_gdot(
    int v, int tid,
    const unsigned short* __restrict__ qT1, const unsigned short* __restrict__ kT1,
    const unsigned short* __restrict__ qT2, const unsigned short* __restrict__ kT2,
    const unsigned short* __restrict__ qT3, const unsigned short* __restrict__ kT3,
    const int* __restrict__ i2, const int* __restrict__ i3, const int* __restrict__ i4,
    float* __restrict__ out, unsigned char* kwin)
{
    const unsigned short *qT, *kT;
    const int* inds;
    int n, wshift, tpbsh, twsh, off;
    if (v < 512) {
        qT = qT1; kT = kT1; inds = i2; n = 16384; wshift = 7; tpbsh = 8; twsh = 4; off = 0;
    } else if (v < 640) {
        qT = qT2; kT = kT2; inds = i3; n = 4096;  wshift = 6; tpbsh = 6; twsh = 3; off = 16384;
    } else {
        qT = qT3; kT = kT3; inds = i4; n = 1024;  wshift = 5; tpbsh = 4; twsh = 2; off = 20480;
    }
    const int lb   = v - ((v < 512) ? 0 : (v < 640) ? 512 : 640);
    const int b    = lb >> tpbsh;
    const int tile = lb & ((1 << tpbsh) - 1);
    const int ty0  = (tile >> twsh) << 3;
    const int tx0  = (tile & ((1 << twsh) - 1)) << 3;
    const int W    = 1 << wshift, Wm1 = W - 1;
    const int ry0  = ty0 - 2, cx0 = tx0 - 2;

    const int pxl = tid >> 2;            // 0..63
    const int sl  = tid & 3;             // 32-ch slice
    const int py = pxl >> 3, px = pxl & 7;
    const int nid = ((ty0 + py) << wshift) + tx0 + px;

    // stage 12x12 window (clamped), 16B chunks, XOR swizzle
    for (int idx = tid; idx < 2304; idx += 256) {
        int slot = idx >> 4, w16 = idx & 15;
        int sy = ry0 + slot / 12, sx = cx0 + slot % 12;
        sy = min(max(sy, 0), Wm1); sx = min(max(sx, 0), Wm1);
        uint4 vv = *(const uint4*)(kT + ((size_t)(b * n + (sy << wshift) + sx) << 7) + (w16 << 3));
        *(uint4*)&kwin[slot * 256 + ((w16 ^ (slot & 7)) << 4)] = vv;
    }

    // q slice -> 32 f32 regs
    float qr[32];
    {
        const uint4* qp = (const uint4*)(qT + (((size_t)(b * n + nid)) << 7) + (sl << 5));
        uint4 q0 = qp[0], q1 = qp[1], q2 = qp[2], q3 = qp[3];
        qr[0]=blo(q0.x); qr[1]=bhi(q0.x); qr[2]=blo(q0.y); qr[3]=bhi(q0.y);
        qr[4]=blo(q0.z); qr[5]=bhi(q0.z); qr[6]=blo(q0.w); qr[7]=bhi(q0.w);
        qr[8]=blo(q1.x); qr[9]=bhi(q1.x); qr[10]=blo(q1.y); qr[11]=bhi(q1.y);
        qr[12]=blo(q1.z); qr[13]=bhi(q1.z); qr[14]=blo(q1.w); qr[15]=bhi(q1.w);
        qr[16]=blo(q2.x); qr[17]=bhi(q2.x); qr[18]=blo(q2.y); qr[19]=bhi(q2.y);
        qr[20]=blo(q2.z); qr[21]=bhi(q2.z); qr[22]=blo(q2.w); qr[23]=bhi(q2.w);
        qr[24]=blo(q3.x); qr[25]=bhi(q3.x); qr[26]=blo(q3.y); qr[27]=bhi(q3.y);
        qr[28]=blo(q3.z); qr[29]=bhi(q3.z); qr[30]=blo(q3.w); qr[31]=bhi(q3.w);
    }
    __syncthreads();

    const int* irow = inds + ((size_t)(b * n + nid) << 5);
    int ia[32];
    {
        const int4* ip = (const int4*)irow;
#pragma unroll
        for (int j = 0; j < 8; ++j) {
            int4 t = ip[j];
            ia[4*j] = t.x; ia[4*j+1] = t.y; ia[4*j+2] = t.z; ia[4*j+3] = t.w;
        }
    }

    const int w16b = sl << 2;
    float res[8];
    float* orow = out + (((size_t)b * NTOT + off + nid) << 5);

#pragma unroll
    for (int s = 0; s < 32; ++s) {
        uint4 k0, k1, k2, k3;
        if (s < 25) {
            int ind = ia[s];
            int iy = ind >> wshift, ix = ind & Wm1;
            int slot = (iy - ry0) * 12 + (ix - cx0);
            int sw = slot & 7;
            const unsigned char* base2 = kwin + slot * 256;
            k0 = *(const uint4*)(base2 + (((w16b + 0) ^ sw) << 4));
            k1 = *(const uint4*)(base2 + (((w16b + 1) ^ sw) << 4));
            k2 = *(const uint4*)(base2 + (((w16b + 2) ^ sw) << 4));
            k3 = *(const uint4*)(base2 + (((w16b + 3) ^ sw) << 4));
        } else {
            const uint4* kp = (const uint4*)(kT + (((size_t)(b * n + ia[s])) << 7) + (sl << 5));
            k0 = kp[0]; k1 = kp[1]; k2 = kp[2]; k3 = kp[3];
        }
        float a = qr[0]*blo(k0.x) + qr[1]*bhi(k0.x) + qr[2]*blo(k0.y) + qr[3]*bhi(k0.y)
                + qr[4]*blo(k0.z) + qr[5]*bhi(k0.z) + qr[6]*blo(k0.w) + qr[7]*bhi(k0.w)
                + qr[8]*blo(k1.x) + qr[9]*bhi(k1.x) + qr[10]*blo(k1.y) + qr[11]*bhi(k1.y)
                + qr[12]*blo(k1.z) + qr[13]*bhi(k1.z) + qr[14]*blo(k1.w) + qr[15]*bhi(k1.w)
                + qr[16]*blo(k2.x) + qr[17]*bhi(k2.x) + qr[18]*blo(k2.y) + qr[19]*bhi(k2.y)
                + qr[20]*blo(k2.z) + qr[21]*bhi(k2.z) + qr[22]*blo(k2.w) + qr[23]*bhi(k2.w)
                + qr[24]*blo(k3.x) + qr[25]*bhi(k3.x) + qr[26]*blo(k3.y) + qr[27]*bhi(k3.y)
                + qr[28]*blo(k3.z) + qr[29]*bhi(k3.z) + qr[30]*blo(k3.w) + qr[31]*bhi(k3.w);
        a += __shfl_xor(a, 1);
        a += __shfl_xor(a, 2);
        if ((s >> 3) == sl) res[s & 7] = a * SCALE;
    }
    float4 r0 = {res[0], res[1], res[2], res[3]};
    float4 r1 = {res[4], res[5], res[6], res[7]};
    *(float4*)(orow + (sl << 3)) = r0;
    *(float4*)(orow + (sl << 3) + 4) = r1;
    __syncthreads();   // protect kwin for next grid-stride iteration
}

// ===========================================================================
// Cooperative fused kernel: 512 blocks x 256 thr, grid.sync between phases.
// ===========================================================================
__global__ __launch_bounds__(256, 2) void fused_k(
    const float* feats, const float* cw, const float* kw, const float* qw,
    const float* cb, const float* kb, const float* qb,
    unsigned short* fpm, unsigned short* wp, float* bias,
    unsigned short* kT1, unsigned short* qT1, unsigned short* kT2,
    unsigned short* qT2, unsigned short* kT3, unsigned short* qT3,
    const int* i2, const int* i3, const int* i4, float* out)
{
    __shared__ __align__(16) unsigned char smem[48128];
    const int tid = threadIdx.x;
    cg::grid_group grid = cg::this_grid();

    for (int v = blockIdx.x; v < 1097; v += 512)
        phase_tp(v, tid, feats, cw, kw, qw, cb, kb, qb, fpm, wp, bias, (float*)smem);

    grid.sync();

    phase_conv(blockIdx.x, tid, fpm, wp, bias, kT1, qT1, kT2, qT2, kT3, qT3, smem);

    grid.sync();

    for (int v = blockIdx.x; v < 672; v += 512)
        phase_gdot(v, tid, qT1, kT1, qT2, kT2, qT3, kT3, i2, i3, i4, out, smem);
}

// ---------------------------------------------------------------------------
// Fallback separate kernels (same device code)
// ---------------------------------------------------------------------------
__global__ __launch_bounds__(256) void tp_sep_k(
    const float* feats, const float* cw, const float* kw, const float* qw,
    const float* cb, const float* kb, const float* qb,
    unsigned short* fpm, unsigned short* wp, float* bias)
{
    __shared__ __align__(16) float fsm[512];
    phase_tp(blockIdx.x, threadIdx.x, feats, cw, kw, qw, cb, kb, qb, fpm, wp, bias, fsm);
}

__global__ __launch_bounds__(256, 2) void conv_sep_k(
    const unsigned short* fpm, const unsigned short* wp, const float* kqbias,
    unsigned short* kT1, unsigned short* qT1, unsigned short* kT2,
    unsigned short* qT2, unsigned short* kT3, unsigned short* qT3)
{
    __shared__ __align__(16) unsigned char smem[48128];
    phase_conv(blockIdx.x, threadIdx.x, fpm, wp, kqbias, kT1, qT1, kT2, qT2, kT3, qT3, smem);
}

__global__ __launch_bounds__(256) void gdot_sep_k(
    const unsigned short* qT1, const unsigned short* kT1,
    const unsigned short* qT2, const unsigned short* kT2,
    const unsigned short* qT3, const unsigned short* kT3,
    const int* i2, const int* i3, const int* i4, float* out)
{
    __shared__ __align__(16) unsigned char kwin[36864];
    phase_gdot(blockIdx.x, threadIdx.x, qT1, kT1, qT2, kT2, qT3, kT3, i2, i3, i4, out, kwin);
}

// ---------------------------------------------------------------------------
extern "C" void kernel_launch(void* const* d_in, const int* in_sizes, int n_in,
                              void* d_out, int out_size, void* d_ws, size_t ws_size,
                              hipStream_t stream)
{
    const float* feats = (const float*)d_in[0];
    const float* cw    = (const float*)d_in[1];
    const float* cb    = (const float*)d_in[2];
    const float* kw    = (const float*)d_in[3];
    const float* kb    = (const float*)d_in[4];
    const float* qw    = (const float*)d_in[5];
    const float* qb    = (const float*)d_in[6];
    const int*   i2    = (const int*)d_in[7];
    const int*   i3    = (const int*)d_in[8];
    const int*   i4    = (const int*)d_in[9];
    float* out = (float*)d_out;

    char* ws = (char*)d_ws;
    unsigned short* wp   = (unsigned short*)ws;                 // 1,179,648 B
    float*          bias = (float*)(ws + 1179648);              //     1,024 B
    unsigned short* fpm  = (unsigned short*)(ws + 1180672);     // 17,305,600 B
    unsigned short* kT1  = (unsigned short*)(ws + 18624512);    // 8,388,608 B
    unsigned short* qT1  = kT1 + 4194304;
    unsigned short* kT2  = qT1 + 4194304;                       // 2,097,152 B
    unsigned short* qT2  = kT2 + 1048576;
    unsigned short* kT3  = qT2 + 1048576;                       //   524,288 B
    unsigned short* qT3  = kT3 + 262144;

    void* args[] = {
        (void*)&feats, (void*)&cw, (void*)&kw, (void*)&qw,
        (void*)&cb, (void*)&kb, (void*)&qb,
        (void*)&fpm, (void*)&wp, (void*)&bias,
        (void*)&kT1, (void*)&qT1, (void*)&kT2, (void*)&qT2,
        (void*)&kT3, (void*)&qT3,
        (void*)&i2, (void*)&i3, (void*)&i4, (void*)&out
    };
    hipError_t err = hipLaunchCooperativeKernel(
        (const void*)fused_k, dim3(512), dim3(256), args, 0, stream);

    if (err != hipSuccess) {
        // fallback: proven 3-dispatch path
        tp_sep_k<<<dim3(1097), 256, 0, stream>>>(feats, cw, kw, qw, cb, kb, qb,
                                                 fpm, wp, bias);
        conv_sep_k<<<dim3(512), 256, 0, stream>>>(fpm, wp, bias, kT1, qT1,
                                                  kT2, qT2, kT3, qT3);
        gdot_sep_k<<<dim3(672), 256, 0, stream>>>(qT1, kT1, qT2, kT2, qT3, kT3,
                                                  i2, i3, i4, out);
    }
}

// Round 11
// 176.554 us; speedup vs baseline: 1.9416x; 1.9416x over previous
//
#include <hip/hip_runtime.h>
#include <cstddef>
#include <cstdint>

typedef __attribute__((ext_vector_type(8))) short short8;
typedef __attribute__((ext_vector_type(4))) float f32x4;

namespace {
constexpr int B_   = 2;
constexpr int HW   = 16384;
constexpr int NTOT = 21504;
constexpr float SCALE = 0.088388347648318447f;  // 128^-0.5
}

__device__ __forceinline__ unsigned short f2bf(float f) {
    unsigned u = __builtin_bit_cast(unsigned, f);
    u += 0x7fffu + ((u >> 16) & 1u);
    return (unsigned short)(u >> 16);
}
__device__ __forceinline__ float bf2f(unsigned short h) {
    return __builtin_bit_cast(float, (unsigned)h << 16);
}
__device__ __forceinline__ float blo(unsigned u) {
    return __builtin_bit_cast(float, u << 16);
}
__device__ __forceinline__ float bhi(unsigned u) {
    return __builtin_bit_cast(float, u & 0xffff0000u);
}
__device__ __forceinline__ unsigned pk2(float a, float b) {
    return (unsigned)f2bf(a) | ((unsigned)f2bf(b) << 16);
}
__device__ __forceinline__ void gload_lds16(const void* g, void* l) {
    __builtin_amdgcn_global_load_lds(
        (const __attribute__((address_space(1))) void*)g,
        (__attribute__((address_space(3))) void*)l, 16, 0, 0);
}

// ---------------------------------------------------------------------------
// tp_k (R7-proven): blocks 0..519 transpose NCHW fp32 -> pixel-major bf16
// (B,130,130,256) with zero borders; 520..1095 weight-pack; 1096 bias.
// ---------------------------------------------------------------------------
__global__ __launch_bounds__(256) void tp_k(
    const float* __restrict__ feats, const float* __restrict__ cw,
    const float* __restrict__ kw, const float* __restrict__ qw,
    const float* __restrict__ cb, const float* __restrict__ kb,
    const float* __restrict__ qb, unsigned short* __restrict__ fpm,
    unsigned short* __restrict__ wp, float* __restrict__ bias)
{
    const int bid = blockIdx.x;
    const int tid = threadIdx.x;

    if (bid < 520) {
        const int b = bid >= 260;
        const int rem = bid - b * 260;
        const int y = rem >> 1, xseg = rem & 1;
        const int lane = tid & 63, cg = tid >> 6;
        const int x = (xseg << 6) + lane;
        const bool inter = (y >= 1 && y <= 128);
        const float* src = feats + (((size_t)b * 256) << 14) + ((y - 1) << 7) + x;
        unsigned short* orow = fpm + ((size_t)(b * 130 + y) * 130 + 1 + x) * 256;

#pragma unroll
        for (int it = 0; it < 8; ++it) {
            const int c0 = (it << 5) + (cg << 3);
            uint4 v = {0u, 0u, 0u, 0u};
            if (inter) {
                float f0 = src[(size_t)(c0 + 0) << 14], f1 = src[(size_t)(c0 + 1) << 14];
                float f2 = src[(size_t)(c0 + 2) << 14], f3 = src[(size_t)(c0 + 3) << 14];
                float f4 = src[(size_t)(c0 + 4) << 14], f5 = src[(size_t)(c0 + 5) << 14];
                float f6 = src[(size_t)(c0 + 6) << 14], f7 = src[(size_t)(c0 + 7) << 14];
                v.x = pk2(f0, f1); v.y = pk2(f2, f3); v.z = pk2(f4, f5); v.w = pk2(f6, f7);
            }
            *(uint4*)(orow + c0) = v;
        }
        if (xseg == 0) {
            uint4 z = {0u, 0u, 0u, 0u};
            if (tid < 32)
                *(uint4*)(fpm + ((size_t)(b * 130 + y) * 130 + 0) * 256 + (tid << 3)) = z;
            else if (tid < 64)
                *(uint4*)(fpm + ((size_t)(b * 130 + y) * 130 + 129) * 256 + ((tid - 32) << 3)) = z;
        }
        return;
    }

    if (bid == 1096) {
        __shared__ float cbv[128];
        if (tid < 128) cbv[tid] = cb[tid];
        __syncthreads();
        const int oc = tid & 127, isQ = tid >> 7;
        const float* wrow = (isQ ? qw : kw) + oc * 128;
        float a = isQ ? qb[oc] : kb[oc];
        for (int j = 0; j < 128; ++j) a += wrow[j] * cbv[j];
        bias[tid] = a;
        return;
    }

    __shared__ float cvec[128][4];
    const int g = bid - 520;
    for (int idx = tid; idx < 512; idx += 256) {
        int j = idx >> 2, q = idx & 3;
        int pair = (g << 2) + q;
        int c = pair / 9, tap = pair - c * 9;
        cvec[j][q] = cw[j * 2304 + c * 9 + tap];
    }
    __syncthreads();
    const int oc = tid & 127, isQ = tid >> 7;
    const float* wrow = (isQ ? qw : kw) + oc * 128;
    float a0 = 0.f, a1 = 0.f, a2 = 0.f, a3 = 0.f;
    for (int j = 0; j < 128; ++j) {
        float wv = wrow[j];
        a0 += wv * cvec[j][0]; a1 += wv * cvec[j][1];
        a2 += wv * cvec[j][2]; a3 += wv * cvec[j][3];
    }
    float accs[4] = {a0, a1, a2, a3};
#pragma unroll
    for (int q = 0; q < 4; ++q) {
        int pair = (g << 2) + q;
        int c = pair / 9, tap = pair - c * 9;
        int chunk = c >> 5, kg = (c >> 3) & 3, i = c & 7;
        int nf = (isQ << 3) + (oc >> 4);
        int lane = (kg << 4) + (oc & 15);
        wp[((size_t)(((chunk * 9 + tap) << 4) + nf) << 9) + (lane << 3) + i] = f2bf(accs[q]);
    }
}

// ---------------------------------------------------------------------------
// conv5_k: oc-split conv for occupancy. 1024 blocks = (tile, key|query half).
// Per block: 8x8 px tile x 128 outputs; 4 waves x 2 nfrags; acc[4][2] (32 VGPR).
// LDS 31.7KB -> 4-5 blocks/CU (was 2). Proven 2-phase staging/inner loop.
// Epilogue: obuf (stride 136) -> vectorized kT1|qT1 + pool2 + pool4 (h-half).
// ---------------------------------------------------------------------------
__global__ __launch_bounds__(256, 4) void conv5_k(
    const unsigned short* __restrict__ fpm, const unsigned short* __restrict__ wp,
    const float* __restrict__ kqbias, unsigned short* __restrict__ kT,
    unsigned short* __restrict__ qT, unsigned short* __restrict__ kT2,
    unsigned short* __restrict__ qT2, unsigned short* __restrict__ kT3,
    unsigned short* __restrict__ qT3)
{
    __shared__ __align__(16) unsigned char abuf[2][7168];
    __shared__ __align__(16) unsigned short obuf[64 * 136];   // 17,408 B

    const int tid = threadIdx.x;
    const int w = tid >> 6, lane = tid & 63;
    const int bid = blockIdx.x;
    const int h = bid & 1;                 // 0 = keys, 1 = queries
    const int t = bid >> 1;                // tile index [0,512)
    const int b = t >> 8, tile = t & 255;
    const int ty0 = (tile >> 4) << 3, tx0 = (tile & 15) << 3;
    const int r = lane & 15, g = lane >> 4;

    const int sp_sub = lane >> 2, sp_o = (lane & 3) << 4;
    const int pbase = (((r >> 3) * 10) + (r & 7)) * 64 + (g << 4);
    const unsigned char* wpB = (const unsigned char*)wp +
        (((h << 3) + (w << 1)) << 10) + (lane << 4);

    f32x4 acc[4][2];
#pragma unroll
    for (int mi = 0; mi < 4; ++mi)
#pragma unroll
        for (int ni = 0; ni < 2; ++ni) acc[mi][ni] = (f32x4){0.f, 0.f, 0.f, 0.f};

    auto stage = [&](int chunk, int buf) {
#pragma unroll
        for (int k = 0; k < 2; ++k) {
            int i = w + (k << 2);
            if (i < 7) {
                int pl0 = (i << 4) + sp_sub;
                int y = (pl0 * 6554) >> 16;
                int x = pl0 - y * 10;
                const unsigned char* src = (const unsigned char*)fpm +
                    (((size_t)((b * 130 + ty0 + y) * 130 + tx0 + x)) << 9) +
                    (chunk << 6) + sp_o;
                gload_lds16(src, &abuf[buf][i << 10]);
            }
        }
    };

    stage(0, 0);
    __syncthreads();

    for (int chunk = 0; chunk < 8; ++chunk) {
        const unsigned char* ab = abuf[chunk & 1];
        if (chunk < 7) stage(chunk + 1, (chunk + 1) & 1);
        const unsigned char* wbase = wpB + (size_t)chunk * 147456;
#pragma unroll
        for (int tap = 0; tap < 9; ++tap) {
            const int dy = tap / 3, dx = tap % 3;
            short8 bf[2];
#pragma unroll
            for (int ni = 0; ni < 2; ++ni)
                bf[ni] = *(const short8*)(wbase + tap * 16384 + (ni << 10));
            short8 af[4];
#pragma unroll
            for (int mi = 0; mi < 4; ++mi)
                af[mi] = *(const short8*)(ab + pbase + (((2 * mi + dy) * 10 + dx) << 6));
#pragma unroll
            for (int mi = 0; mi < 4; ++mi)
#pragma unroll
                for (int ni = 0; ni < 2; ++ni)
                    acc[mi][ni] = __builtin_amdgcn_mfma_f32_16x16x32_bf16(
                        af[mi], bf[ni], acc[mi][ni], 0, 0, 0);
        }
        __syncthreads();
    }

    // epilogue: acc -> obuf (bf16, +bias); local oc = nf_loc*16+col (0..127)
    const int col = lane & 15;
    const int mrow0 = g << 2;
#pragma unroll
    for (int ni = 0; ni < 2; ++ni) {
        const int nf_loc = (w << 1) + ni;
        const float bv = kqbias[(h << 7) + (nf_loc << 4) + col];
#pragma unroll
        for (int mi = 0; mi < 4; ++mi)
#pragma unroll
            for (int reg = 0; reg < 4; ++reg) {
                int m = mrow0 + reg;
                int pxl = ((2 * mi + (m >> 3)) << 3) + (m & 7);
                obuf[pxl * 136 + (nf_loc << 4) + col] = f2bf(acc[mi][ni][reg] + bv);
            }
    }
    __syncthreads();

    unsigned short* dst1 = h ? qT : kT;
    unsigned short* dst2 = h ? qT2 : kT2;
    unsigned short* dst3 = h ? qT3 : kT3;

    // kT1/qT1: thread = (px, 32-oc quarter), 4x uint4
    {
        const int px = tid >> 2, q = tid & 3;
        const int gp = ((ty0 + (px >> 3)) << 7) + tx0 + (px & 7);
        const unsigned short* srow = obuf + px * 136 + (q << 5);
        unsigned short* dp = dst1 + ((((size_t)b << 14) + gp) << 7) + (q << 5);
#pragma unroll
        for (int j = 0; j < 4; ++j)
            *(uint4*)(dp + (j << 3)) = *(const uint4*)(srow + (j << 3));
    }

    // pool2: 16 pooled px x 16 oc-groups of 8
    {
        const int pp = tid >> 4, ocg = tid & 15, oc0 = ocg << 3;
        const int py2 = pp >> 2, px2 = pp & 3;
        const int gp2 = (((ty0 >> 1) + py2) << 6) + (tx0 >> 1) + px2;
        unsigned short* dp = dst2 + (((size_t)b * 4096 + gp2) << 7) + oc0;
        float s0=0,s1=0,s2=0,s3=0,s4=0,s5=0,s6=0,s7=0;
#pragma unroll
        for (int dy = 0; dy < 2; ++dy)
#pragma unroll
            for (int dx = 0; dx < 2; ++dx) {
                int pxl = (((py2 << 1) + dy) << 3) + (px2 << 1) + dx;
                uint4 v = *(const uint4*)(obuf + pxl * 136 + oc0);
                s0 += blo(v.x); s1 += bhi(v.x); s2 += blo(v.y); s3 += bhi(v.y);
                s4 += blo(v.z); s5 += bhi(v.z); s6 += blo(v.w); s7 += bhi(v.w);
            }
        uint4 o;
        o.x = pk2(s0 * 0.25f, s1 * 0.25f); o.y = pk2(s2 * 0.25f, s3 * 0.25f);
        o.z = pk2(s4 * 0.25f, s5 * 0.25f); o.w = pk2(s6 * 0.25f, s7 * 0.25f);
        *(uint4*)dp = o;
    }

    // pool4: 4 pooled px x 16 oc-groups of 8 (threads 0..63)
    if (tid < 64) {
        const int pp = tid >> 4, ocg = tid & 15, oc0 = ocg << 3;
        const int py4 = pp >> 1, px4 = pp & 1;
        const int gp4 = (((ty0 >> 2) + py4) << 5) + (tx0 >> 2) + px4;
        unsigned short* dp = dst3 + (((size_t)b * 1024 + gp4) << 7) + oc0;
        float s0=0,s1=0,s2=0,s3=0,s4=0,s5=0,s6=0,s7=0;
#pragma unroll
        for (int dy = 0; dy < 4; ++dy)
#pragma unroll
            for (int dx = 0; dx < 4; ++dx) {
                int pxl = (((py4 << 2) + dy) << 3) + (px4 << 2) + dx;
                uint4 v = *(const uint4*)(obuf + pxl * 136 + oc0);
                s0 += blo(v.x); s1 += bhi(v.x); s2 += blo(v.y); s3 += bhi(v.y);
                s4 += blo(v.z); s5 += bhi(v.z); s6 += blo(v.w); s7 += bhi(v.w);
            }
        const float f = 0.0625f;
        uint4 o;
        o.x = pk2(s0 * f, s1 * f); o.y = pk2(s2 * f, s3 * f);
        o.z = pk2(s4 * f, s5 * f); o.w = pk2(s6 * f, s7 * f);
        *(uint4*)dp = o;
    }
}

// ---------------------------------------------------------------------------
// gdot_all_k (R7-proven): all 3 levels, 672 blocks x 512 thr.
// ---------------------------------------------------------------------------
__global__ __launch_bounds__(512) void gdot_all_k(
    const unsigned short* __restrict__ qT1, const unsigned short* __restrict__ kT1,
    const unsigned short* __restrict__ qT2, const unsigned short* __restrict__ kT2,
    const unsigned short* __restrict__ qT3, const unsigned short* __restrict__ kT3,
    const int* __restrict__ i2, const int* __restrict__ i3, const int* __restrict__ i4,
    float* __restrict__ out)
{
    __shared__ __align__(16) unsigned char kwin[144 * 256];

    const int raw = blockIdx.x;
    const int bid = (raw & 7) * 84 + (raw >> 3);

    const unsigned short *qT, *kT;
    const int* inds;
    int n, wshift, tpbsh, twsh, off;
    if (bid < 512) {
        qT = qT1; kT = kT1; inds = i2; n = 16384; wshift = 7; tpbsh = 8; twsh = 4; off = 0;
    } else if (bid < 640) {
        qT = qT2; kT = kT2; inds = i3; n = 4096;  wshift = 6; tpbsh = 6; twsh = 3; off = 16384;
    } else {
        qT = qT3; kT = kT3; inds = i4; n = 1024;  wshift = 5; tpbsh = 4; twsh = 2; off = 20480;
    }
    const int lb   = bid - ((bid < 512) ? 0 : (bid < 640) ? 512 : 640);
    const int b    = lb >> tpbsh;
    const int tile = lb & ((1 << tpbsh) - 1);
    const int ty0  = (tile >> twsh) << 3;
    const int tx0  = (tile & ((1 << twsh) - 1)) << 3;
    const int W    = 1 << wshift, Wm1 = W - 1;
    const int ry0  = ty0 - 2, cx0 = tx0 - 2;

    const int tid   = threadIdx.x;
    const int pxl   = tid >> 3;
    const int slice = tid & 7;
    const int py = pxl >> 3, px = pxl & 7;
    const int nid = ((ty0 + py) << wshift) + tx0 + px;

    for (int idx = tid; idx < 2304; idx += 512) {
        int slot = idx >> 4, w16 = idx & 15;
        int sy = ry0 + slot / 12, sx = cx0 + slot % 12;
        sy = min(max(sy, 0), Wm1); sx = min(max(sx, 0), Wm1);
        uint4 v = *(const uint4*)(kT + ((size_t)(b * n + (sy << wshift) + sx) * 128) + (w16 << 3));
        *(uint4*)&kwin[slot * 256 + ((w16 ^ (slot & 7)) << 4)] = v;
    }

    float qr[16];
    {
        const uint4* qp = (const uint4*)(qT + ((size_t)(b * n + nid) * 128) + (slice << 4));
        uint4 q0 = qp[0], q1 = qp[1];
        qr[0] = blo(q0.x); qr[1] = bhi(q0.x); qr[2] = blo(q0.y); qr[3] = bhi(q0.y);
        qr[4] = blo(q0.z); qr[5] = bhi(q0.z); qr[6] = blo(q0.w); qr[7] = bhi(q0.w);
        qr[8] = blo(q1.x); qr[9] = bhi(q1.x); qr[10] = blo(q1.y); qr[11] = bhi(q1.y);
        qr[12] = blo(q1.z); qr[13] = bhi(q1.z); qr[14] = blo(q1.w); qr[15] = bhi(q1.w);
    }
    __syncthreads();

    const int* irow = inds + ((size_t)(b * n + nid) << 5);
    int ia[32];
    {
        const int4* ip = (const int4*)irow;
#pragma unroll
        for (int j = 0; j < 8; ++j) {
            int4 v = ip[j];
            ia[4 * j] = v.x; ia[4 * j + 1] = v.y; ia[4 * j + 2] = v.z; ia[4 * j + 3] = v.w;
        }
    }

    uint4 rk0[7], rk1[7];
#pragma unroll
    for (int rr = 0; rr < 7; ++rr) {
        const uint4* kp = (const uint4*)(kT + (((size_t)(b * n + ia[25 + rr])) << 7) + (slice << 4));
        rk0[rr] = kp[0]; rk1[rr] = kp[1];
    }

    const int w2 = slice << 1;
    float res4[4] = {0.f, 0.f, 0.f, 0.f};
    float* orow = out + (((size_t)b * NTOT + off + nid) << 5);

#pragma unroll
    for (int s = 0; s < 32; ++s) {
        uint4 k0, k1;
        if (s < 25) {
            int ind = ia[s];
            int iy = ind >> wshift, ix = ind & Wm1;
            int slot = (iy - ry0) * 12 + (ix - cx0);
            int sw = slot & 7;
            const unsigned char* base2 = kwin + slot * 256;
            k0 = *(const uint4*)(base2 + ((w2 ^ sw) << 4));
            k1 = *(const uint4*)(base2 + (((w2 + 1) ^ sw) << 4));
        } else {
            k0 = rk0[s - 25]; k1 = rk1[s - 25];
        }
        float a = qr[0] * blo(k0.x) + qr[1] * bhi(k0.x)
                + qr[2] * blo(k0.y) + qr[3] * bhi(k0.y)
                + qr[4] * blo(k0.z) + qr[5] * bhi(k0.z)
                + qr[6] * blo(k0.w) + qr[7] * bhi(k0.w)
                + qr[8] * blo(k1.x) + qr[9] * bhi(k1.x)
                + qr[10] * blo(k1.y) + qr[11] * bhi(k1.y)
                + qr[12] * blo(k1.z) + qr[13] * bhi(k1.z)
                + qr[14] * blo(k1.w) + qr[15] * bhi(k1.w);
        a += __shfl_xor(a, 1);
        a += __shfl_xor(a, 2);
        a += __shfl_xor(a, 4);
        if ((s >> 2) == slice) res4[s & 3] = a * SCALE;
    }
    *(float4*)(orow + (slice << 2)) = *(const float4*)res4;
}

// ---------------------------------------------------------------------------
extern "C" void kernel_launch(void* const* d_in, const int* in_sizes, int n_in,
                              void* d_out, int out_size, void* d_ws, size_t ws_size,
                              hipStream_t stream)
{
    const float* feats = (const float*)d_in[0];
    const float* cw    = (const float*)d_in[1];
    const float* cb    = (const float*)d_in[2];
    const float* kw    = (const float*)d_in[3];
    const float* kb    = (const float*)d_in[4];
    const float* qw    = (const float*)d_in[5];
    const float* qb    = (const float*)d_in[6];
    const int*   i2    = (const int*)d_in[7];
    const int*   i3    = (const int*)d_in[8];
    const int*   i4    = (const int*)d_in[9];
    float* out = (float*)d_out;

    char* ws = (char*)d_ws;
    unsigned short* wp   = (unsigned short*)ws;                 // 1,179,648 B
    float*          bias = (float*)(ws + 1179648);              //     1,024 B
    unsigned short* fpm  = (unsigned short*)(ws + 1180672);     // 17,305,600 B (+slack)
    unsigned short* kT1  = (unsigned short*)(ws + 18624512);    // 8,388,608 B
    unsigned short* qT1  = kT1 + 4194304;
    unsigned short* kT2  = qT1 + 4194304;                       // 2,097,152 B
    unsigned short* qT2  = kT2 + 1048576;
    unsigned short* kT3  = qT2 + 1048576;                       //   524,288 B
    unsigned short* qT3  = kT3 + 262144;

    tp_k<<<dim3(1097), 256, 0, stream>>>(feats, cw, kw, qw, cb, kb, qb,
                                         fpm, wp, bias);
    conv5_k<<<dim3(1024), 256, 0, stream>>>(fpm, wp, bias, kT1, qT1,
                                            kT2, qT2, kT3, qT3);
    gdot_all_k<<<dim3(672), 512, 0, stream>>>(qT1, kT1, qT2, kT2, qT3, kT3,
                                              i2, i3, i4, out);
}